// Round 10
// baseline (441.185 us; speedup 1.0000x reference)
//
#include <hip/hip_runtime.h>
#include <math.h>

#define D_MODEL 2048
#define NH 16
#define Q_LORA 1536
#define KV_LORA 512
#define DN 128
#define DR 64
#define DV 128
#define BB 2
#define SS 2048
#define NROWS (BB*SS)
#define LN_EPS 1e-5f

typedef __attribute__((ext_vector_type(8))) short short8;
typedef __attribute__((ext_vector_type(4))) float f32x4;

__device__ __forceinline__ ushort f2bf(float f) {
    unsigned int u = __float_as_uint(f);
    u = u + 0x7fffu + ((u >> 16) & 1u);   // round-to-nearest-even
    return (ushort)(u >> 16);
}

__device__ __forceinline__ float fexp2(float x) {
#if __has_builtin(__builtin_amdgcn_exp2f)
    return __builtin_amdgcn_exp2f(x);
#else
    return exp2f(x);
#endif
}

// XCD-aware bijective block swizzle (T1): grid sizes are all %8==0.
__device__ __forceinline__ void xcd_swz(int nx, int nwg, int& bx, int& by) {
    int lin = blockIdx.y * nx + blockIdx.x;
    int cpx = nwg >> 3;
    int swz = (lin & 7) * cpx + (lin >> 3);
    bx = swz % nx; by = swz / nx;
}

// ---------------------------------------------------------------------------
// Fused fp32 -> bf16 converter for 5 arrays + padded w_kva + RoPE trig table.
// ---------------------------------------------------------------------------
__device__ __forceinline__ void cv4(const float* __restrict__ s,
                                    ushort* __restrict__ d, long i) {
    float4 v = ((const float4*)s)[i];
    ushort4 o;
    o.x = f2bf(v.x); o.y = f2bf(v.y); o.z = f2bf(v.z); o.w = f2bf(v.w);
    ((ushort4*)d)[i] = o;
}

__global__ __launch_bounds__(256)
void cvt_all(const float* __restrict__ hs,     const float* __restrict__ w_qa,
             const float* __restrict__ w_qb,   const float* __restrict__ w_qrope,
             const float* __restrict__ w_kvb,  const float* __restrict__ w_kva,
             ushort* __restrict__ hs_bf,       ushort* __restrict__ w_qa_bf,
             ushort* __restrict__ w_qb_bf,     ushort* __restrict__ w_qrope_bf,
             ushort* __restrict__ w_kvb_bf,    ushort* __restrict__ w_kva_bf,
             const int* __restrict__ pos,      float2* __restrict__ tab)
{
    long i = (long)blockIdx.x * 256 + threadIdx.x;
    if (i < 2097152) { cv4(hs, hs_bf, i); return; }
    i -= 2097152;
    if (i < 786432) { cv4(w_qa, w_qa_bf, i); return; }
    i -= 786432;
    if (i < 786432) { cv4(w_qb, w_qb_bf, i); return; }
    i -= 786432;
    if (i < 393216) { cv4(w_qrope, w_qrope_bf, i); return; }
    i -= 393216;
    if (i < 524288) { cv4(w_kvb, w_kvb_bf, i); return; }
    i -= 524288;
    if (i < 327680) {
        // w_kva: 576x2048 -> padded 640x2048 (zero fill)
        long e = i * 4;
        int row = (int)(e >> 11), col = (int)(e & 2047);
        ushort4 o;
        if (row < 576) {
            float4 v = *(const float4*)(w_kva + (long)row * 2048 + col);
            o.x = f2bf(v.x); o.y = f2bf(v.y); o.z = f2bf(v.z); o.w = f2bf(v.w);
        } else { o.x = 0; o.y = 0; o.z = 0; o.w = 0; }
        *(ushort4*)(w_kva_bf + (long)row * 2048 + col) = o;
        return;
    }
    i -= 327680;
    if (i >= 65536) return;
    // RoPE cos/sin table: 2048 positions x 32 freqs, fp64-accurate
    int idx = (int)i;
    int fi = idx & 31;
    int s = idx >> 5;
    double ang = (double)pos[s] * exp(-(double)fi * 0.28782313662425572);
    float2 cs;
    cs.x = (float)cos(ang);
    cs.y = (float)sin(ang);
    tab[idx] = cs;
}

// ---------------------------------------------------------------------------
// GEMM cores (single-buffer; T4 2-phase dbuf measured −5.5 µs in round 8).
//  core32: BK=32, 16KB LDS (kept for reference/fallback).
//  core64: BK=64, 32KB LDS, XOR-swizzled, conflict-free. With
//  __launch_bounds__(256,4) (VGPR<=128) it beat core32 on K=2048 (round 7);
//  round 6's core64 regression on gemm_qkv was the unclamped 132-VGPR
//  occupancy cliff — this round tests core64+clamp on gemm_qkv.
// ---------------------------------------------------------------------------
#define GLL16(g, l) \
    __builtin_amdgcn_global_load_lds((const __attribute__((address_space(1))) void*)(g), \
                                     (__attribute__((address_space(3))) void*)(l), 16, 0, 0)

__device__ __forceinline__ void gemm_core32(const ushort* __restrict__ A,
    const ushort* __restrict__ Bp, ushort* As, ushort* Bs,
    int K, int lda, int ldb, int m0, int n0, int tid, f32x4 acc[4][4])
{
    int l = tid & 63, w = tid >> 6;
    int l15 = l & 15, quad = l >> 4;
    int wm = (w >> 1) * 64, wn = (w & 1) * 64;
    int ob = tid * 16;
    int row = ob >> 6, colb = ob & 63;
    const char* ga0 = (const char*)(A  + (long)(m0 + row) * lda)      + colb;
    const char* ga1 = (const char*)(A  + (long)(m0 + row + 64) * lda) + colb;
    const char* gb0 = (const char*)(Bp + (long)(n0 + row) * ldb)      + colb;
    const char* gb1 = (const char*)(Bp + (long)(n0 + row + 64) * ldb) + colb;
    ushort* la0 = As + tid * 8;
    ushort* la1 = As + 2048 + tid * 8;
    ushort* lb0 = Bs + tid * 8;
    ushort* lb1 = Bs + 2048 + tid * 8;

    for (int k0 = 0; k0 < K; k0 += 32) {
        GLL16(ga0, la0); GLL16(ga1, la1);
        GLL16(gb0, lb0); GLL16(gb1, lb1);
        ga0 += 64; ga1 += 64; gb0 += 64; gb1 += 64;
        __syncthreads();
        short8 af[4], bf[4];
        #pragma unroll
        for (int i = 0; i < 4; ++i)
            af[i] = *(const short8*)(As + (wm + i * 16 + l15) * 32 + quad * 8);
        #pragma unroll
        for (int j = 0; j < 4; ++j)
            bf[j] = *(const short8*)(Bs + (wn + j * 16 + l15) * 32 + quad * 8);
        #pragma unroll
        for (int i = 0; i < 4; ++i)
            #pragma unroll
            for (int j = 0; j < 4; ++j)
                acc[i][j] = __builtin_amdgcn_mfma_f32_16x16x32_bf16(
                    af[i], bf[j], acc[i][j], 0, 0, 0);
        __syncthreads();
    }
}

__device__ __forceinline__ void gemm_core64(const ushort* __restrict__ A,
    const ushort* __restrict__ Bp, ushort* As, ushort* Bs,
    int K, int lda, int ldb, int m0, int n0, int tid, f32x4 acc[4][4])
{
    int l = tid & 63, w = tid >> 6;
    int l15 = l & 15, quad = l >> 4;
    int wm = (w >> 1) * 64, wn = (w & 1) * 64;
    int row = tid >> 3;                      // 0..31 (staging row within 32-row slab)
    int cg  = ((tid & 7) ^ (row & 7)) * 8;   // pre-swizzled source chunk (elements)
    const char* ga0 = (const char*)(A  + (long)(m0 + row) * lda + cg);
    const char* ga1 = (const char*)(A  + (long)(m0 + row + 32) * lda + cg);
    const char* ga2 = (const char*)(A  + (long)(m0 + row + 64) * lda + cg);
    const char* ga3 = (const char*)(A  + (long)(m0 + row + 96) * lda + cg);
    const char* gb0 = (const char*)(Bp + (long)(n0 + row) * ldb + cg);
    const char* gb1 = (const char*)(Bp + (long)(n0 + row + 32) * ldb + cg);
    const char* gb2 = (const char*)(Bp + (long)(n0 + row + 64) * ldb + cg);
    const char* gb3 = (const char*)(Bp + (long)(n0 + row + 96) * ldb + cg);
    ushort* la0 = As + tid * 8;          // linear dest: rows 0..31 of [128][64]
    ushort* la1 = As + 2048 + tid * 8;   // rows 32..63
    ushort* la2 = As + 4096 + tid * 8;   // rows 64..95
    ushort* la3 = As + 6144 + tid * 8;   // rows 96..127
    ushort* lb0 = Bs + tid * 8;
    ushort* lb1 = Bs + 2048 + tid * 8;
    ushort* lb2 = Bs + 4096 + tid * 8;
    ushort* lb3 = Bs + 6144 + tid * 8;

    for (int k0 = 0; k0 < K; k0 += 64) {
        GLL16(ga0, la0); GLL16(ga1, la1); GLL16(ga2, la2); GLL16(ga3, la3);
        GLL16(gb0, lb0); GLL16(gb1, lb1); GLL16(gb2, lb2); GLL16(gb3, lb3);
        ga0 += 128; ga1 += 128; ga2 += 128; ga3 += 128;
        gb0 += 128; gb1 += 128; gb2 += 128; gb3 += 128;
        __syncthreads();
        #pragma unroll
        for (int half = 0; half < 2; ++half) {
            short8 af[4], bf[4];
            #pragma unroll
            for (int i = 0; i < 4; ++i) {
                int r = wm + i * 16 + l15;
                af[i] = *(const short8*)(As + r * 64 + ((half * 4 + quad) ^ (l15 & 7)) * 8);
            }
            #pragma unroll
            for (int j = 0; j < 4; ++j) {
                int r = wn + j * 16 + l15;
                bf[j] = *(const short8*)(Bs + r * 64 + ((half * 4 + quad) ^ (l15 & 7)) * 8);
            }
            #pragma unroll
            for (int i = 0; i < 4; ++i)
                #pragma unroll
                for (int j = 0; j < 4; ++j)
                    acc[i][j] = __builtin_amdgcn_mfma_f32_16x16x32_bf16(
                        af[i], bf[j], acc[i][j], 0, 0, 0);
        }
        __syncthreads();
    }
}

// plain fp32-out GEMM (G7) — K=2048, core64, XCD-swizzled grid (512 blocks)
__global__ __launch_bounds__(256, 4)
void gemm_f32out(const ushort* __restrict__ A, const ushort* __restrict__ B,
                 float* __restrict__ C, int K, int lda, int ldb, int ldc)
{
    __shared__ __align__(16) ushort As[128 * 64];
    __shared__ __align__(16) ushort Bs[128 * 64];
    int tid = threadIdx.x;
    int bx, by;
    xcd_swz(gridDim.x, gridDim.x * gridDim.y, bx, by);
    int m0 = by * 128, n0 = bx * 128;
    f32x4 acc[4][4] = {};
    gemm_core64(A, B, As, Bs, K, lda, ldb, m0, n0, tid, acc);
    int l = tid & 63, w = tid >> 6;
    int l15 = l & 15, quad = l >> 4;
    int wm = (w >> 1) * 64, wn = (w & 1) * 64;
    #pragma unroll
    for (int i = 0; i < 4; ++i)
        #pragma unroll
        for (int j = 0; j < 4; ++j)
            #pragma unroll
            for (int r = 0; r < 4; ++r) {
                long gm = m0 + wm + i * 16 + quad * 4 + r;
                long gn = n0 + wn + j * 16 + l15;
                C[gm * ldc + gn] = acc[i][j][r];
            }
}

// merged G1+G4: x-blocks [0,12) -> q_lat_f (N=1536), [12,17) -> kv_mix (N=640)
__global__ __launch_bounds__(256, 4)
void gemm_dual(const ushort* __restrict__ A, const ushort* __restrict__ Bqa,
               const ushort* __restrict__ Bkva, float* __restrict__ Cq,
               float* __restrict__ Ckv)
{
    __shared__ __align__(16) ushort As[128 * 64];
    __shared__ __align__(16) ushort Bs[128 * 64];
    int tid = threadIdx.x;
    int bx, by;
    xcd_swz(gridDim.x, gridDim.x * gridDim.y, bx, by);   // 544 blocks, %8==0
    int m0 = by * 128;
    const ushort* Bp; float* C; int ldc, n0;
    if (bx < 12) { n0 = bx * 128;        Bp = Bqa  + (long)n0 * 2048; C = Cq;  ldc = 1536; }
    else         { n0 = (bx - 12) * 128; Bp = Bkva + (long)n0 * 2048; C = Ckv; ldc = 640; }
    f32x4 acc[4][4] = {};
    gemm_core64(A, Bp, As, Bs, D_MODEL, D_MODEL, D_MODEL, m0, 0, tid, acc);
    int l = tid & 63, w = tid >> 6;
    int l15 = l & 15, quad = l >> 4;
    int wm = (w >> 1) * 64, wn = (w & 1) * 64;
    #pragma unroll
    for (int i = 0; i < 4; ++i)
        #pragma unroll
        for (int j = 0; j < 4; ++j)
            #pragma unroll
            for (int r = 0; r < 4; ++r) {
                long gm = m0 + wm + i * 16 + quad * 4 + r;
                long gn = n0 + wn + j * 16 + l15;
                C[gm * ldc + gn] = acc[i][j][r];
            }
}

// fused q_nope/q_rope GEMM + k_up/v_up GEMM in ONE launch — core64 under
// the (256,4) occupancy clamp (round-6 regression was the unclamped
// 132-VGPR cliff; K=1536 path now does 12 barrier-drains instead of 48).
__global__ __launch_bounds__(256, 4)
void gemm_qkv(const ushort* __restrict__ Aq, const ushort* __restrict__ Bqb,
              const ushort* __restrict__ Bqr, ushort* __restrict__ qfull,
              const float2* __restrict__ tab,
              const ushort* __restrict__ Akv, const ushort* __restrict__ Bkvb,
              ushort* __restrict__ kfull, ushort* __restrict__ vt)
{
    __shared__ __align__(16) ushort As[128 * 64];
    __shared__ __align__(16) ushort Bs[128 * 64];
    int tid = threadIdx.x;
    int bx, by;
    xcd_swz(gridDim.x, gridDim.x * gridDim.y, bx, by);
    int m0 = by * 128;
    int l = tid & 63, w = tid >> 6;
    int l15 = l & 15, quad = l >> 4;
    int wm = (w >> 1) * 64, wn = (w & 1) * 64;
    f32x4 acc[4][4] = {};

    if (bx < 24) {
        int n0 = bx * 128;
        const ushort* Bp = (n0 < 2048) ? Bqb + (long)n0 * Q_LORA
                                       : Bqr + (long)(n0 - 2048) * Q_LORA;
        gemm_core64(Aq, Bp, As, Bs, Q_LORA, Q_LORA, Q_LORA, m0, 0, tid, acc);
        if (n0 < 2048) {
            int head = n0 >> 7;
            #pragma unroll
            for (int i = 0; i < 4; ++i)
                #pragma unroll
                for (int j = 0; j < 4; ++j)
                    #pragma unroll
                    for (int r = 0; r < 4; ++r) {
                        long gm = m0 + wm + i * 16 + quad * 4 + r;
                        int c = wn + j * 16 + l15;
                        qfull[(gm * NH + head) * 192 + c] = f2bf(acc[i][j][r]);
                    }
        } else {
            // rope region: wave's 64-col group = one head's DR=64
            int nb = n0 - 2048;
            int head = (nb + wn) >> 6;
            #pragma unroll
            for (int i = 0; i < 4; ++i)
                #pragma unroll
                for (int j = 0; j < 2; ++j)
                    #pragma unroll
                    for (int r = 0; r < 4; ++r) {
                        long gm = m0 + wm + i * 16 + quad * 4 + r;
                        int ir = j * 16 + l15;
                        int s = (int)(gm & (SS - 1));
                        float2 cs = tab[s * 32 + ir];
                        float x1 = acc[i][j][r], x2 = acc[i][j + 2][r];
                        ushort* op = qfull + (gm * NH + head) * 192 + 128;
                        op[ir]      = f2bf(x1 * cs.x - x2 * cs.y);
                        op[ir + 32] = f2bf(x1 * cs.y + x2 * cs.x);
                    }
        }
    } else {
        int n0 = (bx - 24) * 128;
        const ushort* Bp = Bkvb + (long)n0 * KV_LORA;
        gemm_core64(Akv, Bp, As, Bs, KV_LORA, KV_LORA, KV_LORA, m0, 0, tid, acc);
        if (n0 < 2048) {
            int head = n0 >> 7;
            #pragma unroll
            for (int i = 0; i < 4; ++i)
                #pragma unroll
                for (int j = 0; j < 4; ++j)
                    #pragma unroll
                    for (int r = 0; r < 4; ++r) {
                        long gm = m0 + wm + i * 16 + quad * 4 + r;
                        int c = wn + j * 16 + l15;
                        kfull[(gm * NH + head) * 192 + c] = f2bf(acc[i][j][r]);
                    }
        } else {
            int head = (n0 >> 7) - 16;
            #pragma unroll
            for (int i = 0; i < 4; ++i)
                #pragma unroll
                for (int j = 0; j < 4; ++j) {
                    long gm0 = m0 + wm + i * 16 + quad * 4;
                    int c = wn + j * 16 + l15;        // v channel
                    ushort4 p;
                    p.x = f2bf(acc[i][j][0]); p.y = f2bf(acc[i][j][1]);
                    p.z = f2bf(acc[i][j][2]); p.w = f2bf(acc[i][j][3]);
                    *(ushort4*)(vt + (long)head * 128 * 4096 + (long)c * 4096 + gm0) = p;
                }
        }
    }
}

// ---------------------------------------------------------------------------
// Fused: LN qa rows [0,4096) | LN kva rows [4096,8192) | K-RoPE [8192,8704)
//        | w_o fp32->bf16 convert [8704,12800).
// ---------------------------------------------------------------------------
__global__ __launch_bounds__(256)
void ln_rope(const float* __restrict__ qlf, ushort* __restrict__ qlbf,
             const float* __restrict__ gqa, const float* __restrict__ bqa,
             const float* __restrict__ kvm, ushort* __restrict__ kvbf,
             const float* __restrict__ gkv, const float* __restrict__ bkv,
             ushort* __restrict__ kfull, const float2* __restrict__ tab,
             const float* __restrict__ w_o, ushort* __restrict__ w_o_bf)
{
    __shared__ float sred[4], ssred[4];
    int bid = blockIdx.x, tid = threadIdx.x;
    if (bid < 2 * NROWS) {
        const float* x; ushort* y; const float* g; const float* b; int n;
        if (bid < NROWS) {
            x = qlf + (long)bid * Q_LORA; y = qlbf + (long)bid * Q_LORA;
            g = gqa; b = bqa; n = Q_LORA;
        } else {
            int r = bid - NROWS;
            x = kvm + (long)r * 640; y = kvbf + (long)r * KV_LORA;
            g = gkv; b = bkv; n = KV_LORA;
        }
        float s = 0.f, ss = 0.f;
        for (int i = tid; i < n; i += 256) { float v = x[i]; s += v; ss += v * v; }
        #pragma unroll
        for (int off = 32; off > 0; off >>= 1) {
            s  += __shfl_xor(s, off);
            ss += __shfl_xor(ss, off);
        }
        int wid = tid >> 6, lane = tid & 63;
        if (lane == 0) { sred[wid] = s; ssred[wid] = ss; }
        __syncthreads();
        s  = sred[0] + sred[1] + sred[2] + sred[3];
        ss = ssred[0] + ssred[1] + ssred[2] + ssred[3];
        float mu  = s / n;
        float var = ss / n - mu * mu;
        float r = 1.0f / sqrtf(var + LN_EPS);
        for (int i = tid; i < n; i += 256)
            y[i] = f2bf((x[i] - mu) * r * g[i] + b[i]);
        return;
    }
    if (bid < 2 * NROWS + 512) {
        long idx = (long)(bid - 2 * NROWS) * 256 + tid;
        if (idx >= (long)NROWS * 32) return;
        int i = (int)(idx & 31);
        long rowi = idx >> 5;
        int s = (int)(rowi & (SS - 1));
        float2 cs = tab[s * 32 + i];
        float c = cs.x, sn = cs.y;
        const float* p = kvm + rowi * 640 + 512;
        float x1 = p[i], x2 = p[i + 32];
        ushort v1 = f2bf(x1 * c - x2 * sn);
        ushort v2 = f2bf(x1 * sn + x2 * c);
        ushort* o = kfull + rowi * NH * 192 + 128;
        #pragma unroll
        for (int h = 0; h < NH; ++h) {
            o[h * 192 + i]      = v1;
            o[h * 192 + i + 32] = v2;
        }
        return;
    }
    long i = (long)(bid - (2 * NROWS + 512)) * 256 + tid;
    if (i < 1048576) cv4(w_o, w_o_bf, i);
}

// ---------------------------------------------------------------------------
// MFMA flash attention v3f: 512 thr (8 waves), TQ=128, TK=64.
// v3e + exp/PV interleave: {exp+store j=0,1} -> PV ks=0 -> {exp j=2,3} ->
// PV ks=1. Same-wave lockstep preserves the no-barrier Ps guarantee; the
// second exp batch overlaps PV MFMA, and each pa read waits on 2 stores.
// ---------------------------------------------------------------------------
#define C2LOG 0.10412700456539414f    // log2(e)/sqrt(192)
#define THR2  11.541560327111707f     // 8 nats in bits

__global__ __launch_bounds__(512, 4)
void flash_mfma(const ushort* __restrict__ qf, const ushort* __restrict__ kf,
                const ushort* __restrict__ vt, ushort* __restrict__ attnv)
{
    __shared__ __align__(16) ushort Ks[64 * 192];    // 24.0 KB, swizzled
    __shared__ __align__(16) ushort Vs[128 * 64];    // 16.0 KB, swizzled
    __shared__ __align__(16) ushort Ps[128 * 72];    // 18.0 KB, padded
    int tid = threadIdx.x;
    int w = tid >> 6, l = tid & 63, l15 = l & 15, quad = l >> 4;
    int bh = blockIdx.x;
    int b = bh >> 4, h = bh & 15;
    int q0 = blockIdx.y * 128;

    // Q fragments: wave w owns q rows q0+16w .. q0+16w+15
    const ushort* qp = qf + ((long)(b * SS + q0 + 16 * w + l15) * NH + h) * 192 + quad * 8;
    short8 aq[6];
    #pragma unroll
    for (int kk = 0; kk < 6; ++kk) aq[kk] = *(const short8*)(qp + kk * 32);

    f32x4 o[8] = {};
    float lsum = 0.f;         // running softmax denom for q-row l15
    float mrow = -INFINITY;   // running max (log2-scaled units) for q-row l15

    const ushort* kbase = kf + ((long)(b * SS) * NH + h) * 192;
    const ushort* vbase = vt + (long)h * 128 * 4096 + (long)b * SS;

    // staging thread mapping
    int r0k = tid >> 3, subk = tid & 7;   // K: 64 rows x 24 chunks, 3/thread
    int v0  = tid >> 2, subv = tid & 3;   // V: 128 rows x 8 chunks, 2/thread
    const ushort* kgp = kbase + (long)r0k * (NH * 192);
    const ushort* vgp = vbase + (long)v0 * 4096;

    short8 pk[3], pv[2];
    #pragma unroll
    for (int it = 0; it < 3; ++it)
        pk[it] = *(const short8*)(kgp + (subk + 8 * it) * 8);
    #pragma unroll
    for (int it = 0; it < 2; ++it)
        pv[it] = *(const short8*)(vgp + (subv + 4 * it) * 8);

    int ksw = r0k & 7, vsw = v0 & 7;

    for (int k0 = 0; k0 < SS; k0 += 64) {
        __syncthreads();   // prior compute done reading Ks/Vs
        #pragma unroll
        for (int it = 0; it < 3; ++it)
            *(short8*)&Ks[r0k * 192 + ((subk + 8 * it) ^ ksw) * 8] = pk[it];
        #pragma unroll
        for (int it = 0; it < 2; ++it)
            *(short8*)&Vs[v0 * 64 + ((subv + 4 * it) ^ vsw) * 8] = pv[it];
        __syncthreads();
        if (k0 + 64 < SS) {   // prefetch next tile (loads in flight during compute)
            const ushort* kg = kgp + (long)(k0 + 64) * (NH * 192);
            const ushort* vg = vgp + (k0 + 64);
            #pragma unroll
            for (int it = 0; it < 3; ++it)
                pk[it] = *(const short8*)(kg + (subk + 8 * it) * 8);
            #pragma unroll
            for (int it = 0; it < 2; ++it)
                pv[it] = *(const short8*)(vg + (subv + 4 * it) * 8);
        }

        // swapped QK^T: C[k][q] -> lane holds q-row l15, k = j*16 + quad*4 + r
        f32x4 sc[4] = {};
        __builtin_amdgcn_s_setprio(1);
        #pragma unroll
        for (int kk = 0; kk < 6; ++kk) {
            #pragma unroll
            for (int j = 0; j < 4; ++j) {
                int krow = j * 16 + l15;
                short8 kfr = *(const short8*)&Ks[krow * 192 + (((kk * 4 + quad) ^ (krow & 7))) * 8];
                sc[j] = __builtin_amdgcn_mfma_f32_16x16x32_bf16(kfr, aq[kk], sc[j], 0, 0, 0);
            }
        }
        __builtin_amdgcn_s_setprio(0);

        // online softmax, row-local: in-lane max over 16 raw scores + 2 shfl
        float rmax = fmaxf(
            fmaxf(fmaxf(fmaxf(sc[0][0], sc[0][1]), fmaxf(sc[0][2], sc[0][3])),
                  fmaxf(fmaxf(sc[1][0], sc[1][1]), fmaxf(sc[1][2], sc[1][3]))),
            fmaxf(fmaxf(fmaxf(sc[2][0], sc[2][1]), fmaxf(sc[2][2], sc[2][3])),
                  fmaxf(fmaxf(sc[3][0], sc[3][1]), fmaxf(sc[3][2], sc[3][3]))));
        rmax = fmaxf(rmax, __shfl_xor(rmax, 16));
        rmax = fmaxf(rmax, __shfl_xor(rmax, 32));
        float pmax = rmax * C2LOG;

        // defer-max (T13): rescale only when the running max moved by > 8 nats
        if (__any(pmax > mrow + THR2)) {
            float mnew = fmaxf(mrow, pmax);
            float alpha = fexp2(mrow - mnew);
            mrow = mnew;
            lsum *= alpha;
            // broadcast alpha of q-rows quad*4+r (held by lanes 0..15)
            float a0 = __shfl(alpha, quad * 4 + 0);
            float a1 = __shfl(alpha, quad * 4 + 1);
            float a2 = __shfl(alpha, quad * 4 + 2);
            float a3 = __shfl(alpha, quad * 4 + 3);
            #pragma unroll
            for (int v8 = 0; v8 < 8; ++v8) {
                o[v8][0] *= a0; o[v8][1] *= a1;
                o[v8][2] *= a2; o[v8][3] *= a3;
            }
        }

        // P = 2^(s*C2LOG - mrow); interleave exp-batches with PV halves.
        float tsum = 0.f;
        int prow = (16 * w + l15) * 72 + quad * 4;
        #pragma unroll
        for (int halfp = 0; halfp < 2; ++halfp) {
            #pragma unroll
            for (int jj = 0; jj < 2; ++jj) {
                int j = halfp * 2 + jj;
                float p0 = fexp2(fmaf(sc[j][0], C2LOG, -mrow));
                float p1 = fexp2(fmaf(sc[j][1], C2LOG, -mrow));
                float p2 = fexp2(fmaf(sc[j][2], C2LOG, -mrow));
                float p3 = fexp2(fmaf(sc[j][3], C2LOG, -mrow));
                tsum += (p0 + p1) + (p2 + p3);
                uint2 pu;
                pu.x = (uint)f2bf(p0) | ((uint)f2bf(p1) << 16);
                pu.y = (uint)f2bf(p2) | ((uint)f2bf(p3) << 16);
                *(uint2*)&Ps[prow + j * 16] = pu;
            }
            // PV half (reads exactly the k-range written above; same-wave)
            __builtin_amdgcn_s_setprio(1);
            short8 pa = *(const short8*)&Ps[(16 * w + l15) * 72 + halfp * 32 + quad * 8];
            #pragma unroll
            for (int v8 = 0; v8 < 8; ++v8) {
                int vrow = v8 * 16 + l15;
                short8 bv = *(const short8*)&Vs[vrow * 64 + (((halfp * 4 + quad) ^ (vrow & 7))) * 8];
                o[v8] = __builtin_amdgcn_mfma_f32_16x16x32_bf16(pa, bv, o[v8], 0, 0, 0);
            }
            __builtin_amdgcn_s_setprio(0);
        }
        tsum += __shfl_xor(tsum, 16);
        tsum += __shfl_xor(tsum, 32);
        lsum += tsum;
    }

    #pragma unroll
    for (int r = 0; r < 4; ++r) {
        float Lq = __shfl(lsum, quad * 4 + r);   // lane quad*4+r holds q-row quad*4+r
        float inv = 1.0f / Lq;
        long rowi = (long)(b * SS) + q0 + 16 * w + quad * 4 + r;
        ushort* op = attnv + (rowi * NH + h) * 128;
        #pragma unroll
        for (int v8 = 0; v8 < 8; ++v8)
            op[v8 * 16 + l15] = f2bf(o[v8][r] * inv);
    }
}

// ---------------------------------------------------------------------------

extern "C" void kernel_launch(void* const* d_in, const int* in_sizes, int n_in,
                              void* d_out, int out_size, void* d_ws, size_t ws_size,
                              hipStream_t stream) {
    const float* hs       = (const float*)d_in[0];
    const float* w_qa     = (const float*)d_in[1];
    const float* ln_qa_g  = (const float*)d_in[2];
    const float* ln_qa_b  = (const float*)d_in[3];
    const float* w_qb     = (const float*)d_in[4];
    const float* w_qrope  = (const float*)d_in[5];
    const float* w_kva    = (const float*)d_in[6];
    const float* ln_kva_g = (const float*)d_in[7];
    const float* ln_kva_b = (const float*)d_in[8];
    const float* w_kvb    = (const float*)d_in[9];
    const float* w_o      = (const float*)d_in[10];
    const int*   pos      = (const int*)d_in[11];
    float* out = (float*)d_out;

    char* W = (char*)d_ws;
    ushort* hs_bf     = (ushort*)(W + 0);            // 16,777,216 B
    ushort* w_o_bf    = (ushort*)(W + 0);            //  8,388,608 B (after gemm_dual)
    ushort* w_qa_bf   = (ushort*)(W + 16777216);     //  6,291,456
    ushort* w_qb_bf   = (ushort*)(W + 23068672);     //  6,291,456
    ushort* w_qrope_bf= (ushort*)(W + 29360128);     //  3,145,728
    ushort* w_kva_bf  = (ushort*)(W + 32505856);     //  2,621,440
    ushort* w_kvb_bf  = (ushort*)(W + 35127296);     //  4,194,304
    float*  q_lat_f   = (float*)(W + 39321600);      // 25,165,824
    ushort* q_lat_bf  = (ushort*)(W + 64487424);     // 12,582,912
    float*  kv_mix    = (float*)(W + 77070336);      // 10,485,760
    ushort* kv_lat_bf = (ushort*)(W + 87556096);     //  4,194,304
    ushort* q_full    = (ushort*)(W + 91750400);     // 25,165,824
    ushort* k_full    = (ushort*)(W + 116916224);    // 25,165,824
    ushort* v_exp_t   = (ushort*)(W + 142082048);    // 16,777,216
    ushort* attnv_bf  = (ushort*)(W + 158859264);    // 16,777,216
    float2* rope_tab  = (float2*)(W + 158859264);    //    524,288 (dead before attnv write)

    dim3 blk(256);

    // 1. all converts + rope trig table
    cvt_all<<<dim3(19456), blk, 0, stream>>>(
        hs, w_qa, w_qb, w_qrope, w_kvb, w_kva,
        hs_bf, w_qa_bf, w_qb_bf, w_qrope_bf, w_kvb_bf, w_kva_bf,
        pos, rope_tab);
    // 2. merged G1+G4: q_mixed (N=1536) + kv_mix (N=640)
    gemm_dual<<<dim3(17, 32), blk, 0, stream>>>(
        hs_bf, w_qa_bf, w_kva_bf, q_lat_f, kv_mix);
    // 3. LN qa + LN kva + K-RoPE + w_o convert (hs_bf region now dead)
    ln_rope<<<dim3(12800), blk, 0, stream>>>(
        q_lat_f, q_lat_bf, ln_qa_g, ln_qa_b,
        kv_mix, kv_lat_bf, ln_kva_g, ln_kva_b,
        k_full, rope_tab, w_o, w_o_bf);
    // 4. fused q_nope/q_rope + k_up/v_up GEMMs (core64, 4 blocks/CU clamp)
    gemm_qkv<<<dim3(56, 32), blk, 0, stream>>>(
        q_lat_bf, w_qb_bf, w_qrope_bf, q_full, rope_tab,
        kv_lat_bf, w_kvb_bf, k_full, v_exp_t);
    // 5. flash attention (XCD-affine grid: x=bh, y=q-block)
    flash_mfma<<<dim3(BB * NH, SS / 128), dim3(512), 0, stream>>>(
        q_full, k_full, v_exp_t, attnv_bf);
    // 6. G7: out = attnv @ w_o^T -> fp32
    gemm_f32out<<<dim3(16, 32), blk, 0, stream>>>(
        attnv_bf, w_o_bf, out, NH * DV, NH * DV, NH * DV, D_MODEL);
}

// Round 11
// 428.262 us; speedup vs baseline: 1.0302x; 1.0302x over previous
//
#include <hip/hip_runtime.h>
#include <math.h>

#define D_MODEL 2048
#define NH 16
#define Q_LORA 1536
#define KV_LORA 512
#define DN 128
#define DR 64
#define DV 128
#define BB 2
#define SS 2048
#define NROWS (BB*SS)
#define LN_EPS 1e-5f

typedef __attribute__((ext_vector_type(8))) short short8;
typedef __attribute__((ext_vector_type(4))) float f32x4;

__device__ __forceinline__ ushort f2bf(float f) {
    unsigned int u = __float_as_uint(f);
    u = u + 0x7fffu + ((u >> 16) & 1u);   // round-to-nearest-even
    return (ushort)(u >> 16);
}

__device__ __forceinline__ float fexp2(float x) {
#if __has_builtin(__builtin_amdgcn_exp2f)
    return __builtin_amdgcn_exp2f(x);
#else
    return exp2f(x);
#endif
}

// XCD-aware bijective block swizzle (T1): grid sizes are all %8==0.
__device__ __forceinline__ void xcd_swz(int nx, int nwg, int& bx, int& by) {
    int lin = blockIdx.y * nx + blockIdx.x;
    int cpx = nwg >> 3;
    int swz = (lin & 7) * cpx + (lin >> 3);
    bx = swz % nx; by = swz / nx;
}

// ---------------------------------------------------------------------------
// Fused fp32 -> bf16 converter for 5 arrays + padded w_kva + RoPE trig table.
// ---------------------------------------------------------------------------
__device__ __forceinline__ void cv4(const float* __restrict__ s,
                                    ushort* __restrict__ d, long i) {
    float4 v = ((const float4*)s)[i];
    ushort4 o;
    o.x = f2bf(v.x); o.y = f2bf(v.y); o.z = f2bf(v.z); o.w = f2bf(v.w);
    ((ushort4*)d)[i] = o;
}

__global__ __launch_bounds__(256)
void cvt_all(const float* __restrict__ hs,     const float* __restrict__ w_qa,
             const float* __restrict__ w_qb,   const float* __restrict__ w_qrope,
             const float* __restrict__ w_kvb,  const float* __restrict__ w_kva,
             ushort* __restrict__ hs_bf,       ushort* __restrict__ w_qa_bf,
             ushort* __restrict__ w_qb_bf,     ushort* __restrict__ w_qrope_bf,
             ushort* __restrict__ w_kvb_bf,    ushort* __restrict__ w_kva_bf,
             const int* __restrict__ pos,      float2* __restrict__ tab)
{
    long i = (long)blockIdx.x * 256 + threadIdx.x;
    if (i < 2097152) { cv4(hs, hs_bf, i); return; }
    i -= 2097152;
    if (i < 786432) { cv4(w_qa, w_qa_bf, i); return; }
    i -= 786432;
    if (i < 786432) { cv4(w_qb, w_qb_bf, i); return; }
    i -= 786432;
    if (i < 393216) { cv4(w_qrope, w_qrope_bf, i); return; }
    i -= 393216;
    if (i < 524288) { cv4(w_kvb, w_kvb_bf, i); return; }
    i -= 524288;
    if (i < 327680) {
        // w_kva: 576x2048 -> padded 640x2048 (zero fill)
        long e = i * 4;
        int row = (int)(e >> 11), col = (int)(e & 2047);
        ushort4 o;
        if (row < 576) {
            float4 v = *(const float4*)(w_kva + (long)row * 2048 + col);
            o.x = f2bf(v.x); o.y = f2bf(v.y); o.z = f2bf(v.z); o.w = f2bf(v.w);
        } else { o.x = 0; o.y = 0; o.z = 0; o.w = 0; }
        *(ushort4*)(w_kva_bf + (long)row * 2048 + col) = o;
        return;
    }
    i -= 327680;
    if (i >= 65536) return;
    // RoPE cos/sin table: 2048 positions x 32 freqs, fp64-accurate
    int idx = (int)i;
    int fi = idx & 31;
    int s = idx >> 5;
    double ang = (double)pos[s] * exp(-(double)fi * 0.28782313662425572);
    float2 cs;
    cs.x = (float)cos(ang);
    cs.y = (float)sin(ang);
    tab[idx] = cs;
}

// ---------------------------------------------------------------------------
// GEMM cores (single-buffer; verified best per-kernel assignment, round 9):
//  core32: BK=32, 16KB LDS — gemm_qkv (K=1536/512; core64 tested null r10).
//  core64: BK=64, 32KB LDS, XOR-swizzled — gemm_dual, G7 (K=2048).
// ---------------------------------------------------------------------------
#define GLL16(g, l) \
    __builtin_amdgcn_global_load_lds((const __attribute__((address_space(1))) void*)(g), \
                                     (__attribute__((address_space(3))) void*)(l), 16, 0, 0)

__device__ __forceinline__ void gemm_core32(const ushort* __restrict__ A,
    const ushort* __restrict__ Bp, ushort* As, ushort* Bs,
    int K, int lda, int ldb, int m0, int n0, int tid, f32x4 acc[4][4])
{
    int l = tid & 63, w = tid >> 6;
    int l15 = l & 15, quad = l >> 4;
    int wm = (w >> 1) * 64, wn = (w & 1) * 64;
    int ob = tid * 16;
    int row = ob >> 6, colb = ob & 63;
    const char* ga0 = (const char*)(A  + (long)(m0 + row) * lda)      + colb;
    const char* ga1 = (const char*)(A  + (long)(m0 + row + 64) * lda) + colb;
    const char* gb0 = (const char*)(Bp + (long)(n0 + row) * ldb)      + colb;
    const char* gb1 = (const char*)(Bp + (long)(n0 + row + 64) * ldb) + colb;
    ushort* la0 = As + tid * 8;
    ushort* la1 = As + 2048 + tid * 8;
    ushort* lb0 = Bs + tid * 8;
    ushort* lb1 = Bs + 2048 + tid * 8;

    for (int k0 = 0; k0 < K; k0 += 32) {
        GLL16(ga0, la0); GLL16(ga1, la1);
        GLL16(gb0, lb0); GLL16(gb1, lb1);
        ga0 += 64; ga1 += 64; gb0 += 64; gb1 += 64;
        __syncthreads();
        short8 af[4], bf[4];
        #pragma unroll
        for (int i = 0; i < 4; ++i)
            af[i] = *(const short8*)(As + (wm + i * 16 + l15) * 32 + quad * 8);
        #pragma unroll
        for (int j = 0; j < 4; ++j)
            bf[j] = *(const short8*)(Bs + (wn + j * 16 + l15) * 32 + quad * 8);
        #pragma unroll
        for (int i = 0; i < 4; ++i)
            #pragma unroll
            for (int j = 0; j < 4; ++j)
                acc[i][j] = __builtin_amdgcn_mfma_f32_16x16x32_bf16(
                    af[i], bf[j], acc[i][j], 0, 0, 0);
        __syncthreads();
    }
}

__device__ __forceinline__ void gemm_core64(const ushort* __restrict__ A,
    const ushort* __restrict__ Bp, ushort* As, ushort* Bs,
    int K, int lda, int ldb, int m0, int n0, int tid, f32x4 acc[4][4])
{
    int l = tid & 63, w = tid >> 6;
    int l15 = l & 15, quad = l >> 4;
    int wm = (w >> 1) * 64, wn = (w & 1) * 64;
    int row = tid >> 3;                      // 0..31 (staging row within 32-row slab)
    int cg  = ((tid & 7) ^ (row & 7)) * 8;   // pre-swizzled source chunk (elements)
    const char* ga0 = (const char*)(A  + (long)(m0 + row) * lda + cg);
    const char* ga1 = (const char*)(A  + (long)(m0 + row + 32) * lda + cg);
    const char* ga2 = (const char*)(A  + (long)(m0 + row + 64) * lda + cg);
    const char* ga3 = (const char*)(A  + (long)(m0 + row + 96) * lda + cg);
    const char* gb0 = (const char*)(Bp + (long)(n0 + row) * ldb + cg);
    const char* gb1 = (const char*)(Bp + (long)(n0 + row + 32) * ldb + cg);
    const char* gb2 = (const char*)(Bp + (long)(n0 + row + 64) * ldb + cg);
    const char* gb3 = (const char*)(Bp + (long)(n0 + row + 96) * ldb + cg);
    ushort* la0 = As + tid * 8;          // linear dest: rows 0..31 of [128][64]
    ushort* la1 = As + 2048 + tid * 8;   // rows 32..63
    ushort* la2 = As + 4096 + tid * 8;   // rows 64..95
    ushort* la3 = As + 6144 + tid * 8;   // rows 96..127
    ushort* lb0 = Bs + tid * 8;
    ushort* lb1 = Bs + 2048 + tid * 8;
    ushort* lb2 = Bs + 4096 + tid * 8;
    ushort* lb3 = Bs + 6144 + tid * 8;

    for (int k0 = 0; k0 < K; k0 += 64) {
        GLL16(ga0, la0); GLL16(ga1, la1); GLL16(ga2, la2); GLL16(ga3, la3);
        GLL16(gb0, lb0); GLL16(gb1, lb1); GLL16(gb2, lb2); GLL16(gb3, lb3);
        ga0 += 128; ga1 += 128; ga2 += 128; ga3 += 128;
        gb0 += 128; gb1 += 128; gb2 += 128; gb3 += 128;
        __syncthreads();
        #pragma unroll
        for (int half = 0; half < 2; ++half) {
            short8 af[4], bf[4];
            #pragma unroll
            for (int i = 0; i < 4; ++i) {
                int r = wm + i * 16 + l15;
                af[i] = *(const short8*)(As + r * 64 + ((half * 4 + quad) ^ (l15 & 7)) * 8);
            }
            #pragma unroll
            for (int j = 0; j < 4; ++j) {
                int r = wn + j * 16 + l15;
                bf[j] = *(const short8*)(Bs + r * 64 + ((half * 4 + quad) ^ (l15 & 7)) * 8);
            }
            #pragma unroll
            for (int i = 0; i < 4; ++i)
                #pragma unroll
                for (int j = 0; j < 4; ++j)
                    acc[i][j] = __builtin_amdgcn_mfma_f32_16x16x32_bf16(
                        af[i], bf[j], acc[i][j], 0, 0, 0);
        }
        __syncthreads();
    }
}

// plain fp32-out GEMM (G7) — K=2048, core64, XCD-swizzled grid (512 blocks)
__global__ __launch_bounds__(256, 4)
void gemm_f32out(const ushort* __restrict__ A, const ushort* __restrict__ B,
                 float* __restrict__ C, int K, int lda, int ldb, int ldc)
{
    __shared__ __align__(16) ushort As[128 * 64];
    __shared__ __align__(16) ushort Bs[128 * 64];
    int tid = threadIdx.x;
    int bx, by;
    xcd_swz(gridDim.x, gridDim.x * gridDim.y, bx, by);
    int m0 = by * 128, n0 = bx * 128;
    f32x4 acc[4][4] = {};
    gemm_core64(A, B, As, Bs, K, lda, ldb, m0, n0, tid, acc);
    int l = tid & 63, w = tid >> 6;
    int l15 = l & 15, quad = l >> 4;
    int wm = (w >> 1) * 64, wn = (w & 1) * 64;
    #pragma unroll
    for (int i = 0; i < 4; ++i)
        #pragma unroll
        for (int j = 0; j < 4; ++j)
            #pragma unroll
            for (int r = 0; r < 4; ++r) {
                long gm = m0 + wm + i * 16 + quad * 4 + r;
                long gn = n0 + wn + j * 16 + l15;
                C[gm * ldc + gn] = acc[i][j][r];
            }
}

// merged G1+G4: x-blocks [0,12) -> q_lat_f (N=1536), [12,17) -> kv_mix (N=640)
__global__ __launch_bounds__(256, 4)
void gemm_dual(const ushort* __restrict__ A, const ushort* __restrict__ Bqa,
               const ushort* __restrict__ Bkva, float* __restrict__ Cq,
               float* __restrict__ Ckv)
{
    __shared__ __align__(16) ushort As[128 * 64];
    __shared__ __align__(16) ushort Bs[128 * 64];
    int tid = threadIdx.x;
    int bx, by;
    xcd_swz(gridDim.x, gridDim.x * gridDim.y, bx, by);   // 544 blocks, %8==0
    int m0 = by * 128;
    const ushort* Bp; float* C; int ldc, n0;
    if (bx < 12) { n0 = bx * 128;        Bp = Bqa  + (long)n0 * 2048; C = Cq;  ldc = 1536; }
    else         { n0 = (bx - 12) * 128; Bp = Bkva + (long)n0 * 2048; C = Ckv; ldc = 640; }
    f32x4 acc[4][4] = {};
    gemm_core64(A, Bp, As, Bs, D_MODEL, D_MODEL, D_MODEL, m0, 0, tid, acc);
    int l = tid & 63, w = tid >> 6;
    int l15 = l & 15, quad = l >> 4;
    int wm = (w >> 1) * 64, wn = (w & 1) * 64;
    #pragma unroll
    for (int i = 0; i < 4; ++i)
        #pragma unroll
        for (int j = 0; j < 4; ++j)
            #pragma unroll
            for (int r = 0; r < 4; ++r) {
                long gm = m0 + wm + i * 16 + quad * 4 + r;
                long gn = n0 + wn + j * 16 + l15;
                C[gm * ldc + gn] = acc[i][j][r];
            }
}

// fused q_nope/q_rope GEMM + k_up/v_up GEMM in ONE launch — core32
// (round-10 A/B: core64+clamp was null-to-negative here), 4 blocks/CU,
// XCD-swizzled grid (1792 blocks).
__global__ __launch_bounds__(256, 4)
void gemm_qkv(const ushort* __restrict__ Aq, const ushort* __restrict__ Bqb,
              const ushort* __restrict__ Bqr, ushort* __restrict__ qfull,
              const float2* __restrict__ tab,
              const ushort* __restrict__ Akv, const ushort* __restrict__ Bkvb,
              ushort* __restrict__ kfull, ushort* __restrict__ vt)
{
    __shared__ __align__(16) ushort As[128 * 32];
    __shared__ __align__(16) ushort Bs[128 * 32];
    int tid = threadIdx.x;
    int bx, by;
    xcd_swz(gridDim.x, gridDim.x * gridDim.y, bx, by);
    int m0 = by * 128;
    int l = tid & 63, w = tid >> 6;
    int l15 = l & 15, quad = l >> 4;
    int wm = (w >> 1) * 64, wn = (w & 1) * 64;
    f32x4 acc[4][4] = {};

    if (bx < 24) {
        int n0 = bx * 128;
        const ushort* Bp = (n0 < 2048) ? Bqb + (long)n0 * Q_LORA
                                       : Bqr + (long)(n0 - 2048) * Q_LORA;
        gemm_core32(Aq, Bp, As, Bs, Q_LORA, Q_LORA, Q_LORA, m0, 0, tid, acc);
        if (n0 < 2048) {
            int head = n0 >> 7;
            #pragma unroll
            for (int i = 0; i < 4; ++i)
                #pragma unroll
                for (int j = 0; j < 4; ++j)
                    #pragma unroll
                    for (int r = 0; r < 4; ++r) {
                        long gm = m0 + wm + i * 16 + quad * 4 + r;
                        int c = wn + j * 16 + l15;
                        qfull[(gm * NH + head) * 192 + c] = f2bf(acc[i][j][r]);
                    }
        } else {
            // rope region: wave's 64-col group = one head's DR=64
            int nb = n0 - 2048;
            int head = (nb + wn) >> 6;
            #pragma unroll
            for (int i = 0; i < 4; ++i)
                #pragma unroll
                for (int j = 0; j < 2; ++j)
                    #pragma unroll
                    for (int r = 0; r < 4; ++r) {
                        long gm = m0 + wm + i * 16 + quad * 4 + r;
                        int ir = j * 16 + l15;
                        int s = (int)(gm & (SS - 1));
                        float2 cs = tab[s * 32 + ir];
                        float x1 = acc[i][j][r], x2 = acc[i][j + 2][r];
                        ushort* op = qfull + (gm * NH + head) * 192 + 128;
                        op[ir]      = f2bf(x1 * cs.x - x2 * cs.y);
                        op[ir + 32] = f2bf(x1 * cs.y + x2 * cs.x);
                    }
        }
    } else {
        int n0 = (bx - 24) * 128;
        const ushort* Bp = Bkvb + (long)n0 * KV_LORA;
        gemm_core32(Akv, Bp, As, Bs, KV_LORA, KV_LORA, KV_LORA, m0, 0, tid, acc);
        if (n0 < 2048) {
            int head = n0 >> 7;
            #pragma unroll
            for (int i = 0; i < 4; ++i)
                #pragma unroll
                for (int j = 0; j < 4; ++j)
                    #pragma unroll
                    for (int r = 0; r < 4; ++r) {
                        long gm = m0 + wm + i * 16 + quad * 4 + r;
                        int c = wn + j * 16 + l15;
                        kfull[(gm * NH + head) * 192 + c] = f2bf(acc[i][j][r]);
                    }
        } else {
            int head = (n0 >> 7) - 16;
            #pragma unroll
            for (int i = 0; i < 4; ++i)
                #pragma unroll
                for (int j = 0; j < 4; ++j) {
                    long gm0 = m0 + wm + i * 16 + quad * 4;
                    int c = wn + j * 16 + l15;        // v channel
                    ushort4 p;
                    p.x = f2bf(acc[i][j][0]); p.y = f2bf(acc[i][j][1]);
                    p.z = f2bf(acc[i][j][2]); p.w = f2bf(acc[i][j][3]);
                    *(ushort4*)(vt + (long)head * 128 * 4096 + (long)c * 4096 + gm0) = p;
                }
        }
    }
}

// ---------------------------------------------------------------------------
// Fused: LN qa rows [0,4096) | LN kva rows [4096,8192) | K-RoPE [8192,8704)
//        | w_o fp32->bf16 convert [8704,12800).
// LN rows are now register-cached (one global read instead of two; row
// sizes fixed per branch -> compile-time indices, no scratch).
// ---------------------------------------------------------------------------
__global__ __launch_bounds__(256)
void ln_rope(const float* __restrict__ qlf, ushort* __restrict__ qlbf,
             const float* __restrict__ gqa, const float* __restrict__ bqa,
             const float* __restrict__ kvm, ushort* __restrict__ kvbf,
             const float* __restrict__ gkv, const float* __restrict__ bkv,
             ushort* __restrict__ kfull, const float2* __restrict__ tab,
             const float* __restrict__ w_o, ushort* __restrict__ w_o_bf)
{
    __shared__ float sred[4], ssred[4];
    int bid = blockIdx.x, tid = threadIdx.x;
    if (bid < NROWS) {
        // LN qa: n=1536, 6 elems/thread register-cached
        const float* x = qlf + (long)bid * Q_LORA;
        ushort* y = qlbf + (long)bid * Q_LORA;
        float xv[6];
        #pragma unroll
        for (int t = 0; t < 6; ++t) xv[t] = x[tid + t * 256];
        float s = 0.f, ss = 0.f;
        #pragma unroll
        for (int t = 0; t < 6; ++t) { s += xv[t]; ss += xv[t] * xv[t]; }
        #pragma unroll
        for (int off = 32; off > 0; off >>= 1) {
            s  += __shfl_xor(s, off);
            ss += __shfl_xor(ss, off);
        }
        int wid = tid >> 6, lane = tid & 63;
        if (lane == 0) { sred[wid] = s; ssred[wid] = ss; }
        __syncthreads();
        s  = sred[0] + sred[1] + sred[2] + sred[3];
        ss = ssred[0] + ssred[1] + ssred[2] + ssred[3];
        float mu  = s * (1.0f / Q_LORA);
        float var = ss * (1.0f / Q_LORA) - mu * mu;
        float r = 1.0f / sqrtf(var + LN_EPS);
        #pragma unroll
        for (int t = 0; t < 6; ++t) {
            int i = tid + t * 256;
            y[i] = f2bf((xv[t] - mu) * r * gqa[i] + bqa[i]);
        }
        return;
    }
    if (bid < 2 * NROWS) {
        // LN kva: n=512, 2 elems/thread register-cached
        int rr = bid - NROWS;
        const float* x = kvm + (long)rr * 640;
        ushort* y = kvbf + (long)rr * KV_LORA;
        float x0 = x[tid], x1 = x[tid + 256];
        float s = x0 + x1, ss = x0 * x0 + x1 * x1;
        #pragma unroll
        for (int off = 32; off > 0; off >>= 1) {
            s  += __shfl_xor(s, off);
            ss += __shfl_xor(ss, off);
        }
        int wid = tid >> 6, lane = tid & 63;
        if (lane == 0) { sred[wid] = s; ssred[wid] = ss; }
        __syncthreads();
        s  = sred[0] + sred[1] + sred[2] + sred[3];
        ss = ssred[0] + ssred[1] + ssred[2] + ssred[3];
        float mu  = s * (1.0f / KV_LORA);
        float var = ss * (1.0f / KV_LORA) - mu * mu;
        float r = 1.0f / sqrtf(var + LN_EPS);
        y[tid]       = f2bf((x0 - mu) * r * gkv[tid] + bkv[tid]);
        y[tid + 256] = f2bf((x1 - mu) * r * gkv[tid + 256] + bkv[tid + 256]);
        return;
    }
    if (bid < 2 * NROWS + 512) {
        long idx = (long)(bid - 2 * NROWS) * 256 + tid;
        if (idx >= (long)NROWS * 32) return;
        int i = (int)(idx & 31);
        long rowi = idx >> 5;
        int s = (int)(rowi & (SS - 1));
        float2 cs = tab[s * 32 + i];
        float c = cs.x, sn = cs.y;
        const float* p = kvm + rowi * 640 + 512;
        float x1 = p[i], x2 = p[i + 32];
        ushort v1 = f2bf(x1 * c - x2 * sn);
        ushort v2 = f2bf(x1 * sn + x2 * c);
        ushort* o = kfull + rowi * NH * 192 + 128;
        #pragma unroll
        for (int h = 0; h < NH; ++h) {
            o[h * 192 + i]      = v1;
            o[h * 192 + i + 32] = v2;
        }
        return;
    }
    long i = (long)(bid - (2 * NROWS + 512)) * 256 + tid;
    if (i < 1048576) cv4(w_o, w_o_bf, i);
}

// ---------------------------------------------------------------------------
// MFMA flash attention v3e: 512 thr (8 waves), TQ=128, TK=64.
// (round-9 body; round-10's exp/PV interleave measured +1.5 µs, reverted)
// ---------------------------------------------------------------------------
#define C2LOG 0.10412700456539414f    // log2(e)/sqrt(192)
#define THR2  11.541560327111707f     // 8 nats in bits

__global__ __launch_bounds__(512, 4)
void flash_mfma(const ushort* __restrict__ qf, const ushort* __restrict__ kf,
                const ushort* __restrict__ vt, ushort* __restrict__ attnv)
{
    __shared__ __align__(16) ushort Ks[64 * 192];    // 24.0 KB, swizzled
    __shared__ __align__(16) ushort Vs[128 * 64];    // 16.0 KB, swizzled
    __shared__ __align__(16) ushort Ps[128 * 72];    // 18.0 KB, padded
    int tid = threadIdx.x;
    int w = tid >> 6, l = tid & 63, l15 = l & 15, quad = l >> 4;
    int bh = blockIdx.x;
    int b = bh >> 4, h = bh & 15;
    int q0 = blockIdx.y * 128;

    // Q fragments: wave w owns q rows q0+16w .. q0+16w+15
    const ushort* qp = qf + ((long)(b * SS + q0 + 16 * w + l15) * NH + h) * 192 + quad * 8;
    short8 aq[6];
    #pragma unroll
    for (int kk = 0; kk < 6; ++kk) aq[kk] = *(const short8*)(qp + kk * 32);

    f32x4 o[8] = {};
    float lsum = 0.f;         // running softmax denom for q-row l15
    float mrow = -INFINITY;   // running max (log2-scaled units) for q-row l15

    const ushort* kbase = kf + ((long)(b * SS) * NH + h) * 192;
    const ushort* vbase = vt + (long)h * 128 * 4096 + (long)b * SS;

    // staging thread mapping
    int r0k = tid >> 3, subk = tid & 7;   // K: 64 rows x 24 chunks, 3/thread
    int v0  = tid >> 2, subv = tid & 3;   // V: 128 rows x 8 chunks, 2/thread
    const ushort* kgp = kbase + (long)r0k * (NH * 192);
    const ushort* vgp = vbase + (long)v0 * 4096;

    short8 pk[3], pv[2];
    #pragma unroll
    for (int it = 0; it < 3; ++it)
        pk[it] = *(const short8*)(kgp + (subk + 8 * it) * 8);
    #pragma unroll
    for (int it = 0; it < 2; ++it)
        pv[it] = *(const short8*)(vgp + (subv + 4 * it) * 8);

    int ksw = r0k & 7, vsw = v0 & 7;

    for (int k0 = 0; k0 < SS; k0 += 64) {
        __syncthreads();   // prior compute done reading Ks/Vs
        #pragma unroll
        for (int it = 0; it < 3; ++it)
            *(short8*)&Ks[r0k * 192 + ((subk + 8 * it) ^ ksw) * 8] = pk[it];
        #pragma unroll
        for (int it = 0; it < 2; ++it)
            *(short8*)&Vs[v0 * 64 + ((subv + 4 * it) ^ vsw) * 8] = pv[it];
        __syncthreads();
        if (k0 + 64 < SS) {   // prefetch next tile (loads in flight during compute)
            const ushort* kg = kgp + (long)(k0 + 64) * (NH * 192);
            const ushort* vg = vgp + (k0 + 64);
            #pragma unroll
            for (int it = 0; it < 3; ++it)
                pk[it] = *(const short8*)(kg + (subk + 8 * it) * 8);
            #pragma unroll
            for (int it = 0; it < 2; ++it)
                pv[it] = *(const short8*)(vg + (subv + 4 * it) * 8);
        }

        // swapped QK^T: C[k][q] -> lane holds q-row l15, k = j*16 + quad*4 + r
        f32x4 sc[4] = {};
        __builtin_amdgcn_s_setprio(1);
        #pragma unroll
        for (int kk = 0; kk < 6; ++kk) {
            #pragma unroll
            for (int j = 0; j < 4; ++j) {
                int krow = j * 16 + l15;
                short8 kfr = *(const short8*)&Ks[krow * 192 + (((kk * 4 + quad) ^ (krow & 7))) * 8];
                sc[j] = __builtin_amdgcn_mfma_f32_16x16x32_bf16(kfr, aq[kk], sc[j], 0, 0, 0);
            }
        }
        __builtin_amdgcn_s_setprio(0);

        // online softmax, row-local: in-lane max over 16 raw scores + 2 shfl
        float rmax = fmaxf(
            fmaxf(fmaxf(fmaxf(sc[0][0], sc[0][1]), fmaxf(sc[0][2], sc[0][3])),
                  fmaxf(fmaxf(sc[1][0], sc[1][1]), fmaxf(sc[1][2], sc[1][3]))),
            fmaxf(fmaxf(fmaxf(sc[2][0], sc[2][1]), fmaxf(sc[2][2], sc[2][3])),
                  fmaxf(fmaxf(sc[3][0], sc[3][1]), fmaxf(sc[3][2], sc[3][3]))));
        rmax = fmaxf(rmax, __shfl_xor(rmax, 16));
        rmax = fmaxf(rmax, __shfl_xor(rmax, 32));
        float pmax = rmax * C2LOG;

        // defer-max (T13): rescale only when the running max moved by > 8 nats
        if (__any(pmax > mrow + THR2)) {
            float mnew = fmaxf(mrow, pmax);
            float alpha = fexp2(mrow - mnew);
            mrow = mnew;
            lsum *= alpha;
            // broadcast alpha of q-rows quad*4+r (held by lanes 0..15)
            float a0 = __shfl(alpha, quad * 4 + 0);
            float a1 = __shfl(alpha, quad * 4 + 1);
            float a2 = __shfl(alpha, quad * 4 + 2);
            float a3 = __shfl(alpha, quad * 4 + 3);
            #pragma unroll
            for (int v8 = 0; v8 < 8; ++v8) {
                o[v8][0] *= a0; o[v8][1] *= a1;
                o[v8][2] *= a2; o[v8][3] *= a3;
            }
        }

        // P = 2^(s*C2LOG - mrow), C-packed bf16 pairs, 4x b64 LDS stores;
        // in-lane partial row sum (quads hold disjoint k subsets)
        float tsum = 0.f;
        int prow = (16 * w + l15) * 72 + quad * 4;
        #pragma unroll
        for (int j = 0; j < 4; ++j) {
            float p0 = fexp2(fmaf(sc[j][0], C2LOG, -mrow));
            float p1 = fexp2(fmaf(sc[j][1], C2LOG, -mrow));
            float p2 = fexp2(fmaf(sc[j][2], C2LOG, -mrow));
            float p3 = fexp2(fmaf(sc[j][3], C2LOG, -mrow));
            tsum += (p0 + p1) + (p2 + p3);
            uint2 pu;
            pu.x = (uint)f2bf(p0) | ((uint)f2bf(p1) << 16);
            pu.y = (uint)f2bf(p2) | ((uint)f2bf(p3) << 16);
            *(uint2*)&Ps[prow + j * 16] = pu;
        }
        tsum += __shfl_xor(tsum, 16);
        tsum += __shfl_xor(tsum, 32);
        lsum += tsum;

        // PV (same-wave Ps, no barrier needed)
        __builtin_amdgcn_s_setprio(1);
        #pragma unroll
        for (int ks = 0; ks < 2; ++ks) {
            short8 pa = *(const short8*)&Ps[(16 * w + l15) * 72 + ks * 32 + quad * 8];
            #pragma unroll
            for (int v8 = 0; v8 < 8; ++v8) {
                int vrow = v8 * 16 + l15;
                short8 bv = *(const short8*)&Vs[vrow * 64 + (((ks * 4 + quad) ^ (vrow & 7))) * 8];
                o[v8] = __builtin_amdgcn_mfma_f32_16x16x32_bf16(pa, bv, o[v8], 0, 0, 0);
            }
        }
        __builtin_amdgcn_s_setprio(0);
    }

    #pragma unroll
    for (int r = 0; r < 4; ++r) {
        float Lq = __shfl(lsum, quad * 4 + r);   // lane quad*4+r holds q-row quad*4+r
        float inv = 1.0f / Lq;
        long rowi = (long)(b * SS) + q0 + 16 * w + quad * 4 + r;
        ushort* op = attnv + (rowi * NH + h) * 128;
        #pragma unroll
        for (int v8 = 0; v8 < 8; ++v8)
            op[v8 * 16 + l15] = f2bf(o[v8][r] * inv);
    }
}

// ---------------------------------------------------------------------------

extern "C" void kernel_launch(void* const* d_in, const int* in_sizes, int n_in,
                              void* d_out, int out_size, void* d_ws, size_t ws_size,
                              hipStream_t stream) {
    const float* hs       = (const float*)d_in[0];
    const float* w_qa     = (const float*)d_in[1];
    const float* ln_qa_g  = (const float*)d_in[2];
    const float* ln_qa_b  = (const float*)d_in[3];
    const float* w_qb     = (const float*)d_in[4];
    const float* w_qrope  = (const float*)d_in[5];
    const float* w_kva    = (const float*)d_in[6];
    const float* ln_kva_g = (const float*)d_in[7];
    const float* ln_kva_b = (const float*)d_in[8];
    const float* w_kvb    = (const float*)d_in[9];
    const float* w_o      = (const float*)d_in[10];
    const int*   pos      = (const int*)d_in[11];
    float* out = (float*)d_out;

    char* W = (char*)d_ws;
    ushort* hs_bf     = (ushort*)(W + 0);            // 16,777,216 B
    ushort* w_o_bf    = (ushort*)(W + 0);            //  8,388,608 B (after gemm_dual)
    ushort* w_qa_bf   = (ushort*)(W + 16777216);     //  6,291,456
    ushort* w_qb_bf   = (ushort*)(W + 23068672);     //  6,291,456
    ushort* w_qrope_bf= (ushort*)(W + 29360128);     //  3,145,728
    ushort* w_kva_bf  = (ushort*)(W + 32505856);     //  2,621,440
    ushort* w_kvb_bf  = (ushort*)(W + 35127296);     //  4,194,304
    float*  q_lat_f   = (float*)(W + 39321600);      // 25,165,824
    ushort* q_lat_bf  = (ushort*)(W + 64487424);     // 12,582,912
    float*  kv_mix    = (float*)(W + 77070336);      // 10,485,760
    ushort* kv_lat_bf = (ushort*)(W + 87556096);     //  4,194,304
    ushort* q_full    = (ushort*)(W + 91750400);     // 25,165,824
    ushort* k_full    = (ushort*)(W + 116916224);    // 25,165,824
    ushort* v_exp_t   = (ushort*)(W + 142082048);    // 16,777,216
    ushort* attnv_bf  = (ushort*)(W + 158859264);    // 16,777,216
    float2* rope_tab  = (float2*)(W + 158859264);    //    524,288 (dead before attnv write)

    dim3 blk(256);

    // 1. all converts + rope trig table
    cvt_all<<<dim3(19456), blk, 0, stream>>>(
        hs, w_qa, w_qb, w_qrope, w_kvb, w_kva,
        hs_bf, w_qa_bf, w_qb_bf, w_qrope_bf, w_kvb_bf, w_kva_bf,
        pos, rope_tab);
    // 2. merged G1+G4: q_mixed (N=1536) + kv_mix (N=640)
    gemm_dual<<<dim3(17, 32), blk, 0, stream>>>(
        hs_bf, w_qa_bf, w_kva_bf, q_lat_f, kv_mix);
    // 3. LN qa + LN kva + K-RoPE + w_o convert (hs_bf region now dead)
    ln_rope<<<dim3(12800), blk, 0, stream>>>(
        q_lat_f, q_lat_bf, ln_qa_g, ln_qa_b,
        kv_mix, kv_lat_bf, ln_kva_g, ln_kva_b,
        k_full, rope_tab, w_o, w_o_bf);
    // 4. fused q_nope/q_rope + k_up/v_up GEMMs (core32, 4 blocks/CU)
    gemm_qkv<<<dim3(56, 32), blk, 0, stream>>>(
        q_lat_bf, w_qb_bf, w_qrope_bf, q_full, rope_tab,
        kv_lat_bf, w_kvb_bf, k_full, v_exp_t);
    // 5. flash attention (XCD-affine grid: x=bh, y=q-block)
    flash_mfma<<<dim3(BB * NH, SS / 128), dim3(512), 0, stream>>>(
        q_full, k_full, v_exp_t, attnv_bf);
    // 6. G7: out = attnv @ w_o^T -> fp32
    gemm_f32out<<<dim3(16, 32), blk, 0, stream>>>(
        attnv_bf, w_o_bf, out, NH * DV, NH * DV, NH * DV, D_MODEL);
}